// Round 10
// baseline (82.349 us; speedup 1.0000x reference)
//
#include <hip/hip_runtime.h>

// VQ nearest-codebook: x [16,64,64,64] NCHW fp32, emb [512,64] fp32.
// out = concat(one_hot [65536,512] f32, quantized [16,64,64,64] f32).
//
// Round-10 = round-6 (best, 52.8us) + two latency fixes found via r9's split
// ablation (compute kernel alone ~= fused kernel time; writes ~free):
//  1) fp64 tie-refine de-serialized: xq preloaded to regs (unrolled,
//     coalesced), e rows as float4, unrolled fp64 groups. Was a rolled
//     64-iter loop with per-iter dependent gather waits (~6-13us serial
//     block tail); now ~1-2us. Same math, same order, same threshold.
//  2) chunk compute in 2-tile groups: 8 ds_reads issued together, 24 MFMAs
//     over 4 independent acc chains (was 2) -> ds/MFMA latency hidden
//     within the wave.
// Write pacing structure (r6) untouched: per-chunk zero slices after the
// stage barrier, __syncthreads pacing (r7/r8 proved removing/staggering it
// causes 45-60MB write+fetch amplification), scatter+quant at the end.

constexpr int D    = 64;
constexpr int K    = 512;
constexpr int N    = 65536;
constexpr int HW   = 4096;
constexpr int TPB  = 256;
constexpr int PIXB = 64;
constexpr int NCHUNK = 4;            // 128 codes per chunk

typedef __attribute__((ext_vector_type(8))) short bf16x8;
typedef __attribute__((ext_vector_type(4))) short short4v;
typedef __attribute__((ext_vector_type(4))) float f32x4;

__device__ inline unsigned short f2bf(float f) {           // RNE f32->bf16
    unsigned u = __builtin_bit_cast(unsigned, f);
    unsigned r = u + 0x7fffu + ((u >> 16) & 1u);
    return (unsigned short)(r >> 16);
}
__device__ inline float bf2f(unsigned short h) {
    unsigned u = ((unsigned)h) << 16;
    return __builtin_bit_cast(float, u);
}

// cheap top-2 update (min/max sort; exact ties resolved by the fp64 refine)
__device__ inline void top2u(float s, int code, float& bs, float& ss, int& bi, int& si) {
    bool c1 = s < bs;
    bool c2 = s < ss;
    float mx = fmaxf(bs, s);
    bs = fminf(bs, s);
    ss = fminf(ss, mx);
    si = c1 ? bi : (c2 ? code : si);
    bi = c1 ? code : bi;
}
// insert with explicit index tie-break (cross-lane/cross-wave merges)
__device__ inline void top2_ins(float os, int oi, float& bs, float& ss, int& bi, int& si) {
    bool c1 = (os < bs) || (os == bs && oi < bi);
    bool c2 = (os < ss) || (os == ss && oi < si);
    ss = c1 ? bs : (c2 ? os : ss);
    si = c1 ? bi : (c2 ? oi : si);
    bs = c1 ? os : bs;
    bi = c1 ? oi : bi;
}

// ---------------- prep: emb -> frag-ordered hi/lo bf16 + e_sq ----------------
// ebuf shorts: chunk*16384 + sec*4096 + tile*512 + g*128 + cl*8 + j
__global__ __launch_bounds__(TPB) void vq_prep(
    const float* __restrict__ emb, short* __restrict__ ebuf, float* __restrict__ esq)
{
    const int t    = blockIdx.x * TPB + threadIdx.x;   // 8192 threads
    const int code = t >> 4;
    const int q    = t & 15;
    const int d0   = q * 4;
    float4 f = ((const float4*)emb)[t];
    unsigned short h0 = f2bf(f.x), h1 = f2bf(f.y), h2 = f2bf(f.z), h3 = f2bf(f.w);
    short4v hv = { (short)h0, (short)h1, (short)h2, (short)h3 };
    short4v lv = { (short)f2bf(f.x - bf2f(h0)), (short)f2bf(f.y - bf2f(h1)),
                   (short)f2bf(f.z - bf2f(h2)), (short)f2bf(f.w - bf2f(h3)) };
    const int chunk = code >> 7, cc = code & 127, tile = cc >> 4, cl = cc & 15;
    const int g = (d0 & 31) >> 3, j0 = d0 & 7, secH = (d0 >= 32) ? 1 : 0;
    const int base = chunk * 16384 + tile * 512 + g * 128 + cl * 8 + j0;
    *(short4v*)&ebuf[base + secH * 4096]       = hv;
    *(short4v*)&ebuf[base + (2 + secH) * 4096] = lv;
    float pe = f.x * f.x + f.y * f.y + f.z * f.z + f.w * f.w;
    pe += __shfl_xor(pe, 1);
    pe += __shfl_xor(pe, 2);
    pe += __shfl_xor(pe, 4);
    pe += __shfl_xor(pe, 8);
    if (q == 0) esq[code] = pe;
}

// ---------------- main ----------------
__global__ __launch_bounds__(TPB, 4) void vq_main(
    const float* __restrict__ x, const float* __restrict__ emb,
    const short* __restrict__ ebuf, const float* __restrict__ esq,
    float* __restrict__ enc, float* __restrict__ quant)
{
    __shared__ short s_e[16384];                  // 32 KB chunk buffer
    __shared__ float s_esq[K];                    // 2 KB
    __shared__ float s_tbs[2][PIXB], s_tss[2][PIXB];
    __shared__ int   s_tbi[2][PIXB], s_tsi[2][PIXB];
    __shared__ int   s_idx[PIXB];

    const int tid  = threadIdx.x;
    const int lane = tid & 63;
    const int wave = __builtin_amdgcn_readfirstlane(tid >> 6);
    const int g    = lane >> 4;
    const int cl   = lane & 15;
    const int ph   = wave & 1;                    // pixel half (32 px)
    const int kh   = wave >> 1;                   // K half (tiles 0-3 / 4-7)
    const int wloc = ph * 32;

    const int pixbase = blockIdx.x * PIXB;
    const int b   = pixbase >> 12;
    const int hw0 = pixbase & (HW - 1);
    const float* xb = x + (size_t)b * D * HW;

    // ---- prologue loads: x (oldest), esq, chunk-0 prefetch. NO stores yet. ----
    float xv0[16], xv1[16];
    #pragma unroll
    for (int j = 0; j < 8; ++j) {
        const size_t o0 = (size_t)(g * 8 + j) * HW + hw0 + wloc + cl;
        const size_t o1 = (size_t)(32 + g * 8 + j) * HW + hw0 + wloc + cl;
        xv0[j]     = xb[o0];       xv0[8 + j] = xb[o1];
        xv1[j]     = xb[o0 + 16];  xv1[8 + j] = xb[o1 + 16];
    }
    const float eq_a = esq[tid];
    const float eq_b = esq[tid + 256];

    const bf16x8* gsrc = (const bf16x8*)ebuf;     // 16B units; chunk stride 2048
    bf16x8 stg[8];
    #pragma unroll
    for (int i = 0; i < 8; ++i) stg[i] = gsrc[i * 256 + tid];

    s_esq[tid]       = eq_a;
    s_esq[tid + 256] = eq_b;

    // ---- pack A fragments hi/lo ----
    bf16x8 a0h0, a0h1, a0l0, a0l1, a1h0, a1h1, a1l0, a1l1;
    #pragma unroll
    for (int j = 0; j < 8; ++j) {
        unsigned short h;
        h = f2bf(xv0[j]);     a0h0[j] = (short)h; a0l0[j] = (short)f2bf(xv0[j]     - bf2f(h));
        h = f2bf(xv0[8 + j]); a0h1[j] = (short)h; a0l1[j] = (short)f2bf(xv0[8 + j] - bf2f(h));
        h = f2bf(xv1[j]);     a1h0[j] = (short)h; a1l0[j] = (short)f2bf(xv1[j]     - bf2f(h));
        h = f2bf(xv1[8 + j]); a1h1[j] = (short)h; a1l1[j] = (short)f2bf(xv1[8 + j] - bf2f(h));
    }

    float bs0[4], ss0[4], bs1[4], ss1[4];
    int   bi0[4], si0[4], bi1[4], si1[4];
    #pragma unroll
    for (int r = 0; r < 4; ++r) {
        bs0[r] = ss0[r] = bs1[r] = ss1[r] = 3.4e38f;
        bi0[r] = si0[r] = bi1[r] = si1[r] = 0x7fffffff;
    }

    bf16x8* se8 = (bf16x8*)s_e;
    float4* encb4 = (float4*)(enc + (size_t)pixbase * K);
    const float4 z4 = {0.f, 0.f, 0.f, 0.f};

    for (int chunk = 0; chunk < NCHUNK; ++chunk) {
        // ---- stage regs -> LDS (conflict-free contiguous b128) ----
        #pragma unroll
        for (int i = 0; i < 8; ++i) se8[i * 256 + tid] = stg[i];
        __syncthreads();                           // LDS visible + store pacing drain

        // ---- next-chunk prefetch FIRST (older than this chunk's stores) ----
        if (chunk + 1 < NCHUNK) {
            #pragma unroll
            for (int i = 0; i < 8; ++i)
                stg[i] = gsrc[(chunk + 1) * 2048 + i * 256 + tid];
        }
        __builtin_amdgcn_sched_barrier(0);
        // ---- this chunk's one-hot zero slice (32 KB/block, fire-and-forget) ----
        #pragma unroll
        for (int it = 0; it < 8; ++it)
            encb4[chunk * 2048 + it * 256 + tid] = z4;
        __builtin_amdgcn_sched_barrier(0);

        // ---- compute: 2 groups of 2 tiles; 8 ds_reads + 24 MFMA (4 chains) ----
        #pragma unroll
        for (int grp = 0; grp < 2; ++grp) {
            const int t8a = kh * 4 + grp * 2;
            const int t8b = t8a + 1;
            const short* pa = s_e + t8a * 512 + g * 128 + cl * 8;
            const short* pb = s_e + t8b * 512 + g * 128 + cl * 8;
            bf16x8 ta_h0 = *(const bf16x8*)pa;
            bf16x8 ta_h1 = *(const bf16x8*)(pa + 4096);
            bf16x8 ta_l0 = *(const bf16x8*)(pa + 8192);
            bf16x8 ta_l1 = *(const bf16x8*)(pa + 12288);
            bf16x8 tb_h0 = *(const bf16x8*)pb;
            bf16x8 tb_h1 = *(const bf16x8*)(pb + 4096);
            bf16x8 tb_l0 = *(const bf16x8*)(pb + 8192);
            bf16x8 tb_l1 = *(const bf16x8*)(pb + 12288);
            f32x4 ca0 = {0.f, 0.f, 0.f, 0.f};
            f32x4 ca1 = {0.f, 0.f, 0.f, 0.f};
            f32x4 cb0 = {0.f, 0.f, 0.f, 0.f};
            f32x4 cb1 = {0.f, 0.f, 0.f, 0.f};
            ca0 = __builtin_amdgcn_mfma_f32_16x16x32_bf16(a0h0, ta_h0, ca0, 0, 0, 0);
            cb0 = __builtin_amdgcn_mfma_f32_16x16x32_bf16(a0h0, tb_h0, cb0, 0, 0, 0);
            ca1 = __builtin_amdgcn_mfma_f32_16x16x32_bf16(a1h0, ta_h0, ca1, 0, 0, 0);
            cb1 = __builtin_amdgcn_mfma_f32_16x16x32_bf16(a1h0, tb_h0, cb1, 0, 0, 0);
            ca0 = __builtin_amdgcn_mfma_f32_16x16x32_bf16(a0h1, ta_h1, ca0, 0, 0, 0);
            cb0 = __builtin_amdgcn_mfma_f32_16x16x32_bf16(a0h1, tb_h1, cb0, 0, 0, 0);
            ca1 = __builtin_amdgcn_mfma_f32_16x16x32_bf16(a1h1, ta_h1, ca1, 0, 0, 0);
            cb1 = __builtin_amdgcn_mfma_f32_16x16x32_bf16(a1h1, tb_h1, cb1, 0, 0, 0);
            ca0 = __builtin_amdgcn_mfma_f32_16x16x32_bf16(a0l0, ta_h0, ca0, 0, 0, 0);
            cb0 = __builtin_amdgcn_mfma_f32_16x16x32_bf16(a0l0, tb_h0, cb0, 0, 0, 0);
            ca1 = __builtin_amdgcn_mfma_f32_16x16x32_bf16(a1l0, ta_h0, ca1, 0, 0, 0);
            cb1 = __builtin_amdgcn_mfma_f32_16x16x32_bf16(a1l0, tb_h0, cb1, 0, 0, 0);
            ca0 = __builtin_amdgcn_mfma_f32_16x16x32_bf16(a0l1, ta_h1, ca0, 0, 0, 0);
            cb0 = __builtin_amdgcn_mfma_f32_16x16x32_bf16(a0l1, tb_h1, cb0, 0, 0, 0);
            ca1 = __builtin_amdgcn_mfma_f32_16x16x32_bf16(a1l1, ta_h1, ca1, 0, 0, 0);
            cb1 = __builtin_amdgcn_mfma_f32_16x16x32_bf16(a1l1, tb_h1, cb1, 0, 0, 0);
            ca0 = __builtin_amdgcn_mfma_f32_16x16x32_bf16(a0h0, ta_l0, ca0, 0, 0, 0);
            cb0 = __builtin_amdgcn_mfma_f32_16x16x32_bf16(a0h0, tb_l0, cb0, 0, 0, 0);
            ca1 = __builtin_amdgcn_mfma_f32_16x16x32_bf16(a1h0, ta_l0, ca1, 0, 0, 0);
            cb1 = __builtin_amdgcn_mfma_f32_16x16x32_bf16(a1h0, tb_l0, cb1, 0, 0, 0);
            ca0 = __builtin_amdgcn_mfma_f32_16x16x32_bf16(a0h1, ta_l1, ca0, 0, 0, 0);
            cb0 = __builtin_amdgcn_mfma_f32_16x16x32_bf16(a0h1, tb_l1, cb0, 0, 0, 0);
            ca1 = __builtin_amdgcn_mfma_f32_16x16x32_bf16(a1h1, ta_l1, ca1, 0, 0, 0);
            cb1 = __builtin_amdgcn_mfma_f32_16x16x32_bf16(a1h1, tb_l1, cb1, 0, 0, 0);
            const int codeA = chunk * 128 + t8a * 16 + cl;
            const int codeB = codeA + 16;
            const float eqA = s_esq[codeA];
            const float eqB = s_esq[codeB];
            #pragma unroll
            for (int r = 0; r < 4; ++r) {
                top2u(fmaf(-2.0f, ca0[r], eqA), codeA, bs0[r], ss0[r], bi0[r], si0[r]);
                top2u(fmaf(-2.0f, ca1[r], eqA), codeA, bs1[r], ss1[r], bi1[r], si1[r]);
                top2u(fmaf(-2.0f, cb0[r], eqB), codeB, bs0[r], ss0[r], bi0[r], si0[r]);
                top2u(fmaf(-2.0f, cb1[r], eqB), codeB, bs1[r], ss1[r], bi1[r], si1[r]);
            }
        }
        __syncthreads();                           // reads done + store pacing drain
    }

    // ---- cross-lane top-2 merge (over cl within each g-group) ----
    #pragma unroll
    for (int r = 0; r < 4; ++r) {
        for (int m = 1; m <= 8; m <<= 1) {
            float obs, oss; int obi, osi;
            obs = __shfl_xor(bs0[r], m); obi = __shfl_xor(bi0[r], m);
            oss = __shfl_xor(ss0[r], m); osi = __shfl_xor(si0[r], m);
            top2_ins(obs, obi, bs0[r], ss0[r], bi0[r], si0[r]);
            top2_ins(oss, osi, bs0[r], ss0[r], bi0[r], si0[r]);
            obs = __shfl_xor(bs1[r], m); obi = __shfl_xor(bi1[r], m);
            oss = __shfl_xor(ss1[r], m); osi = __shfl_xor(si1[r], m);
            top2_ins(obs, obi, bs1[r], ss1[r], bi1[r], si1[r]);
            top2_ins(oss, osi, bs1[r], ss1[r], bi1[r], si1[r]);
        }
    }
    if (cl == 0) {
        #pragma unroll
        for (int r = 0; r < 4; ++r) {
            const int p0 = wloc + g * 4 + r;          // C/D row = (lane>>4)*4+reg
            s_tbs[kh][p0] = bs0[r]; s_tss[kh][p0] = ss0[r];
            s_tbi[kh][p0] = bi0[r]; s_tsi[kh][p0] = si0[r];
            const int p1 = p0 + 16;
            s_tbs[kh][p1] = bs1[r]; s_tss[kh][p1] = ss1[r];
            s_tbi[kh][p1] = bi1[r]; s_tsi[kh][p1] = si1[r];
        }
    }
    __syncthreads();

    // ---- combine K halves + fp64 refinement of near-ties (ILP version) ----
    if (tid < PIXB) {
        float bs = s_tbs[0][tid], ss = s_tss[0][tid];
        int   bi = s_tbi[0][tid], si = s_tsi[0][tid];
        top2_ins(s_tbs[1][tid], s_tbi[1][tid], bs, ss, bi, si);
        top2_ins(s_tss[1][tid], s_tsi[1][tid], bs, ss, bi, si);
        int fin = bi;
        if (ss - bs < 0.125f) {
            const float* xq = xb + hw0 + tid;
            // preload xq (coalesced across active lanes, all loads in flight)
            float xr[D];
            #pragma unroll
            for (int d = 0; d < D; ++d) xr[d] = xq[(size_t)d * HW];
            const float4* e0 = (const float4*)(emb + (size_t)bi * D);
            const float4* e1 = (const float4*)(emb + (size_t)si * D);
            double sa = 0.0, sb = 0.0;
            #pragma unroll 4
            for (int q = 0; q < 16; ++q) {
                float4 v0 = e0[q];
                float4 v1 = e1[q];
                const int d0 = q * 4;
                double x0 = (double)xr[d0], x1 = (double)xr[d0 + 1];
                double x2 = (double)xr[d0 + 2], x3 = (double)xr[d0 + 3];
                sa += (double)v0.x * ((double)v0.x - 2.0 * x0)
                    + (double)v0.y * ((double)v0.y - 2.0 * x1)
                    + (double)v0.z * ((double)v0.z - 2.0 * x2)
                    + (double)v0.w * ((double)v0.w - 2.0 * x3);
                sb += (double)v1.x * ((double)v1.x - 2.0 * x0)
                    + (double)v1.y * ((double)v1.y - 2.0 * x1)
                    + (double)v1.z * ((double)v1.z - 2.0 * x2)
                    + (double)v1.w * ((double)v1.w - 2.0 * x3);
            }
            if (sb < sa || (sb == sa && si < bi)) fin = si;
        }
        s_idx[tid] = fin;
    }
    __syncthreads();   // zeros retired + s_idx visible

    // ---- 1.0 scatter ----
    if (tid < PIXB)
        enc[(size_t)(pixbase + tid) * K + s_idx[tid]] = 1.0f;

    // ---- quant writes: coalesced per-channel segments ----
    {
        const int p   = tid & 63;
        const int ch0 = (tid >> 6) * 16;
        const int id  = s_idx[p];
        float* qb = quant + (size_t)b * D * HW + hw0 + p;
        #pragma unroll
        for (int j = 0; j < 16; ++j)
            qb[(size_t)(ch0 + j) * HW] = emb[(size_t)id * D + ch0 + j];
    }
}

extern "C" void kernel_launch(void* const* d_in, const int* in_sizes, int n_in,
                              void* d_out, int out_size, void* d_ws, size_t ws_size,
                              hipStream_t stream)
{
    const float* x   = (const float*)d_in[0];
    const float* emb = (const float*)d_in[1];
    float* enc   = (float*)d_out;
    float* quant = (float*)d_out + (size_t)N * K;

    short* ebuf = (short*)d_ws;                          // 128 KB frag-ordered hi/lo
    float* esq  = (float*)(ebuf + (size_t)K * D * 2);    // 2 KB

    hipLaunchKernelGGL(vq_prep, dim3(K * D / 4 / TPB), dim3(TPB), 0, stream,
                       emb, ebuf, esq);
    hipLaunchKernelGGL(vq_main, dim3(N / PIXB), dim3(TPB), 0, stream,
                       x, emb, ebuf, esq, enc, quant);
}

// Round 11
// 59.113 us; speedup vs baseline: 1.3931x; 1.3931x over previous
//
#include <hip/hip_runtime.h>

// VQ nearest-codebook: x [16,64,64,64] NCHW fp32, emb [512,64] fp32.
// out = concat(one_hot [65536,512] f32, quantized [16,64,64,64] f32).
//
// Round-11 = EXACT round-6 skeleton (best, 52.8us: per-chunk zero slices,
// __syncthreads store pacing, prefetch-before-stores, esq in LDS, 12-MFMA
// tiles with 2 acc chains) + ONE change: the fp64 tie-refine tail is
// parallelized across all 256 threads (4 threads x 16 dims per pixel,
// batched loads -> 1 wait instead of 64 dependent waits; partials combined
// in LDS reusing the dead chunk buffer). r10 proved the xr[64]-preload +
// 8-frag-regroup version spills to scratch (+100MB WRITE, +56MB FETCH) —
// this version adds ~zero register pressure.

constexpr int D    = 64;
constexpr int K    = 512;
constexpr int N    = 65536;
constexpr int HW   = 4096;
constexpr int TPB  = 256;
constexpr int PIXB = 64;
constexpr int NCHUNK = 4;            // 128 codes per chunk

typedef __attribute__((ext_vector_type(8))) short bf16x8;
typedef __attribute__((ext_vector_type(4))) short short4v;
typedef __attribute__((ext_vector_type(4))) float f32x4;

__device__ inline unsigned short f2bf(float f) {           // RNE f32->bf16
    unsigned u = __builtin_bit_cast(unsigned, f);
    unsigned r = u + 0x7fffu + ((u >> 16) & 1u);
    return (unsigned short)(r >> 16);
}
__device__ inline float bf2f(unsigned short h) {
    unsigned u = ((unsigned)h) << 16;
    return __builtin_bit_cast(float, u);
}

// cheap top-2 update (min/max sort; exact ties resolved by the fp64 refine)
__device__ inline void top2u(float s, int code, float& bs, float& ss, int& bi, int& si) {
    bool c1 = s < bs;
    bool c2 = s < ss;
    float mx = fmaxf(bs, s);
    bs = fminf(bs, s);
    ss = fminf(ss, mx);
    si = c1 ? bi : (c2 ? code : si);
    bi = c1 ? code : bi;
}
// insert with explicit index tie-break (cross-lane/cross-wave merges)
__device__ inline void top2_ins(float os, int oi, float& bs, float& ss, int& bi, int& si) {
    bool c1 = (os < bs) || (os == bs && oi < bi);
    bool c2 = (os < ss) || (os == ss && oi < si);
    ss = c1 ? bs : (c2 ? os : ss);
    si = c1 ? bi : (c2 ? oi : si);
    bs = c1 ? os : bs;
    bi = c1 ? oi : bi;
}

// ---------------- prep: emb -> frag-ordered hi/lo bf16 + e_sq ----------------
// ebuf shorts: chunk*16384 + sec*4096 + tile*512 + g*128 + cl*8 + j
__global__ __launch_bounds__(TPB) void vq_prep(
    const float* __restrict__ emb, short* __restrict__ ebuf, float* __restrict__ esq)
{
    const int t    = blockIdx.x * TPB + threadIdx.x;   // 8192 threads
    const int code = t >> 4;
    const int q    = t & 15;
    const int d0   = q * 4;
    float4 f = ((const float4*)emb)[t];
    unsigned short h0 = f2bf(f.x), h1 = f2bf(f.y), h2 = f2bf(f.z), h3 = f2bf(f.w);
    short4v hv = { (short)h0, (short)h1, (short)h2, (short)h3 };
    short4v lv = { (short)f2bf(f.x - bf2f(h0)), (short)f2bf(f.y - bf2f(h1)),
                   (short)f2bf(f.z - bf2f(h2)), (short)f2bf(f.w - bf2f(h3)) };
    const int chunk = code >> 7, cc = code & 127, tile = cc >> 4, cl = cc & 15;
    const int g = (d0 & 31) >> 3, j0 = d0 & 7, secH = (d0 >= 32) ? 1 : 0;
    const int base = chunk * 16384 + tile * 512 + g * 128 + cl * 8 + j0;
    *(short4v*)&ebuf[base + secH * 4096]       = hv;
    *(short4v*)&ebuf[base + (2 + secH) * 4096] = lv;
    float pe = f.x * f.x + f.y * f.y + f.z * f.z + f.w * f.w;
    pe += __shfl_xor(pe, 1);
    pe += __shfl_xor(pe, 2);
    pe += __shfl_xor(pe, 4);
    pe += __shfl_xor(pe, 8);
    if (q == 0) esq[code] = pe;
}

// ---------------- main ----------------
__global__ __launch_bounds__(TPB, 4) void vq_main(
    const float* __restrict__ x, const float* __restrict__ emb,
    const short* __restrict__ ebuf, const float* __restrict__ esq,
    float* __restrict__ enc, float* __restrict__ quant)
{
    __shared__ short s_e[16384];                  // 32 KB chunk buffer (reused as refine scratch)
    __shared__ float s_esq[K];                    // 2 KB
    __shared__ float s_tbs[2][PIXB], s_tss[2][PIXB];
    __shared__ int   s_tbi[2][PIXB], s_tsi[2][PIXB];
    __shared__ int   s_idx[PIXB];

    const int tid  = threadIdx.x;
    const int lane = tid & 63;
    const int wave = __builtin_amdgcn_readfirstlane(tid >> 6);
    const int g    = lane >> 4;
    const int cl   = lane & 15;
    const int ph   = wave & 1;                    // pixel half (32 px)
    const int kh   = wave >> 1;                   // K half (tiles 0-3 / 4-7)
    const int wloc = ph * 32;

    const int pixbase = blockIdx.x * PIXB;
    const int b   = pixbase >> 12;
    const int hw0 = pixbase & (HW - 1);
    const float* xb = x + (size_t)b * D * HW;

    // ---- prologue loads: x (oldest), esq, chunk-0 prefetch. NO stores yet. ----
    float xv0[16], xv1[16];
    #pragma unroll
    for (int j = 0; j < 8; ++j) {
        const size_t o0 = (size_t)(g * 8 + j) * HW + hw0 + wloc + cl;
        const size_t o1 = (size_t)(32 + g * 8 + j) * HW + hw0 + wloc + cl;
        xv0[j]     = xb[o0];       xv0[8 + j] = xb[o1];
        xv1[j]     = xb[o0 + 16];  xv1[8 + j] = xb[o1 + 16];
    }
    const float eq_a = esq[tid];
    const float eq_b = esq[tid + 256];

    const bf16x8* gsrc = (const bf16x8*)ebuf;     // 16B units; chunk stride 2048
    bf16x8 stg[8];
    #pragma unroll
    for (int i = 0; i < 8; ++i) stg[i] = gsrc[i * 256 + tid];

    s_esq[tid]       = eq_a;
    s_esq[tid + 256] = eq_b;

    // ---- pack A fragments hi/lo ----
    bf16x8 a0h0, a0h1, a0l0, a0l1, a1h0, a1h1, a1l0, a1l1;
    #pragma unroll
    for (int j = 0; j < 8; ++j) {
        unsigned short h;
        h = f2bf(xv0[j]);     a0h0[j] = (short)h; a0l0[j] = (short)f2bf(xv0[j]     - bf2f(h));
        h = f2bf(xv0[8 + j]); a0h1[j] = (short)h; a0l1[j] = (short)f2bf(xv0[8 + j] - bf2f(h));
        h = f2bf(xv1[j]);     a1h0[j] = (short)h; a1l0[j] = (short)f2bf(xv1[j]     - bf2f(h));
        h = f2bf(xv1[8 + j]); a1h1[j] = (short)h; a1l1[j] = (short)f2bf(xv1[8 + j] - bf2f(h));
    }

    float bs0[4], ss0[4], bs1[4], ss1[4];
    int   bi0[4], si0[4], bi1[4], si1[4];
    #pragma unroll
    for (int r = 0; r < 4; ++r) {
        bs0[r] = ss0[r] = bs1[r] = ss1[r] = 3.4e38f;
        bi0[r] = si0[r] = bi1[r] = si1[r] = 0x7fffffff;
    }

    bf16x8* se8 = (bf16x8*)s_e;
    float4* encb4 = (float4*)(enc + (size_t)pixbase * K);
    const float4 z4 = {0.f, 0.f, 0.f, 0.f};

    for (int chunk = 0; chunk < NCHUNK; ++chunk) {
        // ---- stage regs -> LDS (conflict-free contiguous b128) ----
        #pragma unroll
        for (int i = 0; i < 8; ++i) se8[i * 256 + tid] = stg[i];
        __syncthreads();                           // LDS visible + store pacing drain

        // ---- next-chunk prefetch FIRST (older than this chunk's stores) ----
        if (chunk + 1 < NCHUNK) {
            #pragma unroll
            for (int i = 0; i < 8; ++i)
                stg[i] = gsrc[(chunk + 1) * 2048 + i * 256 + tid];
        }
        __builtin_amdgcn_sched_barrier(0);
        // ---- this chunk's one-hot zero slice (32 KB/block, fire-and-forget) ----
        #pragma unroll
        for (int it = 0; it < 8; ++it)
            encb4[chunk * 2048 + it * 256 + tid] = z4;
        __builtin_amdgcn_sched_barrier(0);

        // ---- compute 4 tiles (r6 form: 4 ds_reads + 12 MFMA, 2 chains) ----
        #pragma unroll
        for (int tt = 0; tt < 4; ++tt) {
            const int t8 = kh * 4 + tt;
            const short* pb = s_e + t8 * 512 + g * 128 + cl * 8;
            bf16x8 bh0 = *(const bf16x8*)pb;
            bf16x8 bh1 = *(const bf16x8*)(pb + 4096);
            bf16x8 bl0 = *(const bf16x8*)(pb + 8192);
            bf16x8 bl1 = *(const bf16x8*)(pb + 12288);
            f32x4 c0 = {0.f, 0.f, 0.f, 0.f};
            f32x4 c1 = {0.f, 0.f, 0.f, 0.f};
            c0 = __builtin_amdgcn_mfma_f32_16x16x32_bf16(a0h0, bh0, c0, 0, 0, 0);
            c1 = __builtin_amdgcn_mfma_f32_16x16x32_bf16(a1h0, bh0, c1, 0, 0, 0);
            c0 = __builtin_amdgcn_mfma_f32_16x16x32_bf16(a0h1, bh1, c0, 0, 0, 0);
            c1 = __builtin_amdgcn_mfma_f32_16x16x32_bf16(a1h1, bh1, c1, 0, 0, 0);
            c0 = __builtin_amdgcn_mfma_f32_16x16x32_bf16(a0l0, bh0, c0, 0, 0, 0);
            c1 = __builtin_amdgcn_mfma_f32_16x16x32_bf16(a1l0, bh0, c1, 0, 0, 0);
            c0 = __builtin_amdgcn_mfma_f32_16x16x32_bf16(a0l1, bh1, c0, 0, 0, 0);
            c1 = __builtin_amdgcn_mfma_f32_16x16x32_bf16(a1l1, bh1, c1, 0, 0, 0);
            c0 = __builtin_amdgcn_mfma_f32_16x16x32_bf16(a0h0, bl0, c0, 0, 0, 0);
            c1 = __builtin_amdgcn_mfma_f32_16x16x32_bf16(a1h0, bl0, c1, 0, 0, 0);
            c0 = __builtin_amdgcn_mfma_f32_16x16x32_bf16(a0h1, bl1, c0, 0, 0, 0);
            c1 = __builtin_amdgcn_mfma_f32_16x16x32_bf16(a1h1, bl1, c1, 0, 0, 0);
            const int code = chunk * 128 + t8 * 16 + cl;
            const float eq = s_esq[code];
            #pragma unroll
            for (int r = 0; r < 4; ++r) {
                top2u(fmaf(-2.0f, c0[r], eq), code, bs0[r], ss0[r], bi0[r], si0[r]);
                top2u(fmaf(-2.0f, c1[r], eq), code, bs1[r], ss1[r], bi1[r], si1[r]);
            }
        }
        __syncthreads();                           // reads done + store pacing drain
    }

    // ---- cross-lane top-2 merge (over cl within each g-group) ----
    #pragma unroll
    for (int r = 0; r < 4; ++r) {
        for (int m = 1; m <= 8; m <<= 1) {
            float obs, oss; int obi, osi;
            obs = __shfl_xor(bs0[r], m); obi = __shfl_xor(bi0[r], m);
            oss = __shfl_xor(ss0[r], m); osi = __shfl_xor(si0[r], m);
            top2_ins(obs, obi, bs0[r], ss0[r], bi0[r], si0[r]);
            top2_ins(oss, osi, bs0[r], ss0[r], bi0[r], si0[r]);
            obs = __shfl_xor(bs1[r], m); obi = __shfl_xor(bi1[r], m);
            oss = __shfl_xor(ss1[r], m); osi = __shfl_xor(si1[r], m);
            top2_ins(obs, obi, bs1[r], ss1[r], bi1[r], si1[r]);
            top2_ins(oss, osi, bs1[r], ss1[r], bi1[r], si1[r]);
        }
    }
    if (cl == 0) {
        #pragma unroll
        for (int r = 0; r < 4; ++r) {
            const int p0 = wloc + g * 4 + r;          // C/D row = (lane>>4)*4+reg
            s_tbs[kh][p0] = bs0[r]; s_tss[kh][p0] = ss0[r];
            s_tbi[kh][p0] = bi0[r]; s_tsi[kh][p0] = si0[r];
            const int p1 = p0 + 16;
            s_tbs[kh][p1] = bs1[r]; s_tss[kh][p1] = ss1[r];
            s_tbi[kh][p1] = bi1[r]; s_tsi[kh][p1] = si1[r];
        }
    }
    __syncthreads();

    // ---- refine scratch layout in the dead chunk buffer (s_e) ----
    int*    s_cbi  = (int*)s_e;                    // [64]
    int*    s_csi  = s_cbi + 64;                   // [64]
    float*  s_cgap = (float*)(s_csi + 64);         // [64]
    double* s_pd0  = (double*)(s_e + 1024);        // [256]
    double* s_pd1  = s_pd0 + 256;                  // [256]

    // ---- combine K halves (tid<64), publish candidates ----
    if (tid < PIXB) {
        float bs = s_tbs[0][tid], ss = s_tss[0][tid];
        int   bi = s_tbi[0][tid], si = s_tsi[0][tid];
        top2_ins(s_tbs[1][tid], s_tbi[1][tid], bs, ss, bi, si);
        top2_ins(s_tss[1][tid], s_tsi[1][tid], bs, ss, bi, si);
        s_cbi[tid]  = bi;
        s_csi[tid]  = si;
        s_cgap[tid] = ss - bs;
    }
    __syncthreads();

    // ---- parallel fp64 refine: 4 threads x 16 dims per pixel, batched loads ----
    {
        const int p   = tid >> 2;                  // pixel 0..63
        const int sub = tid & 3;                   // 16-dim slab
        if (s_cgap[p] < 0.125f) {
            const int i0 = s_cbi[p], i1 = s_csi[p];
            const float*  xq = xb + hw0 + p;
            const float4* e0 = (const float4*)(emb + (size_t)i0 * D + sub * 16);
            const float4* e1 = (const float4*)(emb + (size_t)i1 * D + sub * 16);
            double sa = 0.0, sb = 0.0;
            #pragma unroll
            for (int q = 0; q < 4; ++q) {          // 4 dims per step, independent loads
                const int d0 = sub * 16 + q * 4;
                float4 v0 = e0[q];
                float4 v1 = e1[q];
                float  x0 = xq[(size_t)(d0 + 0) * HW];
                float  x1 = xq[(size_t)(d0 + 1) * HW];
                float  x2 = xq[(size_t)(d0 + 2) * HW];
                float  x3 = xq[(size_t)(d0 + 3) * HW];
                sa += (double)v0.x * ((double)v0.x - 2.0 * (double)x0)
                    + (double)v0.y * ((double)v0.y - 2.0 * (double)x1)
                    + (double)v0.z * ((double)v0.z - 2.0 * (double)x2)
                    + (double)v0.w * ((double)v0.w - 2.0 * (double)x3);
                sb += (double)v1.x * ((double)v1.x - 2.0 * (double)x0)
                    + (double)v1.y * ((double)v1.y - 2.0 * (double)x1)
                    + (double)v1.z * ((double)v1.z - 2.0 * (double)x2)
                    + (double)v1.w * ((double)v1.w - 2.0 * (double)x3);
            }
            s_pd0[tid] = sa;
            s_pd1[tid] = sb;
        }
    }
    __syncthreads();

    // ---- final decision (tid<64) ----
    if (tid < PIXB) {
        int fin = s_cbi[tid];
        if (s_cgap[tid] < 0.125f) {
            const int i0 = fin, i1 = s_csi[tid];
            double sa = s_pd0[tid * 4] + s_pd0[tid * 4 + 1] + s_pd0[tid * 4 + 2] + s_pd0[tid * 4 + 3];
            double sb = s_pd1[tid * 4] + s_pd1[tid * 4 + 1] + s_pd1[tid * 4 + 2] + s_pd1[tid * 4 + 3];
            if (sb < sa || (sb == sa && i1 < i0)) fin = i1;
        }
        s_idx[tid] = fin;
    }
    __syncthreads();   // zeros retired + s_idx visible

    // ---- 1.0 scatter ----
    if (tid < PIXB)
        enc[(size_t)(pixbase + tid) * K + s_idx[tid]] = 1.0f;

    // ---- quant writes: coalesced per-channel segments ----
    {
        const int p   = tid & 63;
        const int ch0 = (tid >> 6) * 16;
        const int id  = s_idx[p];
        float* qb = quant + (size_t)b * D * HW + hw0 + p;
        #pragma unroll
        for (int j = 0; j < 16; ++j)
            qb[(size_t)(ch0 + j) * HW] = emb[(size_t)id * D + ch0 + j];
    }
}

extern "C" void kernel_launch(void* const* d_in, const int* in_sizes, int n_in,
                              void* d_out, int out_size, void* d_ws, size_t ws_size,
                              hipStream_t stream)
{
    const float* x   = (const float*)d_in[0];
    const float* emb = (const float*)d_in[1];
    float* enc   = (float*)d_out;
    float* quant = (float*)d_out + (size_t)N * K;

    short* ebuf = (short*)d_ws;                          // 128 KB frag-ordered hi/lo
    float* esq  = (float*)(ebuf + (size_t)K * D * 2);    // 2 KB

    hipLaunchKernelGGL(vq_prep, dim3(K * D / 4 / TPB), dim3(TPB), 0, stream,
                       emb, ebuf, esq);
    hipLaunchKernelGGL(vq_main, dim3(N / PIXB), dim3(TPB), 0, stream,
                       x, emb, ebuf, esq, enc, quant);
}